// Round 9
// baseline (1910.204 us; speedup 1.0000x reference)
//
#include <hip/hip_runtime.h>
#include <stdint.h>
#include <stddef.h>

typedef _Float16 f16;
typedef _Float16 f16x2 __attribute__((ext_vector_type(2)));
typedef _Float16 f16x8 __attribute__((ext_vector_type(8)));
typedef float f32x16 __attribute__((ext_vector_type(16)));
typedef uint32_t u32x4 __attribute__((ext_vector_type(4)));

#define INNER_SZ 4225
#define NQ 164          // ksteps: 160 quad (sym-folded, row-rounded) + 4 linear
#define PD 8            // register prefetch depth (ksteps)

// ---------------- prep: symmetric fold + granule-packed f16 ----------------
// Wf2 layout: [q][2048B] = [q][ng(2)][64 granules(16B)][8 f16], granule G = 2c+h
// (c = output col within ng-half, h = k-half). No swizzle (registers, not LDS).
// kstep q<160: quad row i, sub s: coeff[j = s*16 + h*8 + e] =
//   j<i: W[o][i,j]+W[o][j,i] ; j==i: W[o][i,i] ; j>i: 0
// kstep 160..163: linear terms W[o][0,j]+W[o][j,0].
__global__ __launch_bounds__(256) void cm_prep(const float* __restrict__ W,
                                               const float* __restrict__ bias,
                                               f16* __restrict__ Wf2,
                                               float* __restrict__ cvec) {
  int idx = blockIdx.x * 256 + threadIdx.x;
  if (idx < NQ * 1024) {
    int q   = idx >> 10;
    int r10 = idx & 1023;
    int ngh = r10 >> 9;
    int rr  = r10 & 511;
    int G   = rr >> 3;
    int e   = rr & 7;
    int c = G >> 1, h = G & 1;
    int o = ngh * 32 + c;
    int kl = h * 8 + e;
    float v = 0.f;
    if (q < 160) {
      int b, start;
      if (q < 16)      { b = 0; start = 0;  }
      else if (q < 48) { b = 1; start = 16; }
      else if (q < 96) { b = 2; start = 48; }
      else             { b = 3; start = 96; }
      int rel = q - start;
      int i = 16 * b + rel / (b + 1);
      int s = rel % (b + 1);
      int j = s * 16 + kl;
      if (j < i)
        v = W[o * INNER_SZ + (i + 1) * 65 + (j + 1)] +
            W[o * INNER_SZ + (j + 1) * 65 + (i + 1)];
      else if (j == i)
        v = W[o * INNER_SZ + (i + 1) * 65 + (i + 1)];
    } else {
      int j = (q - 160) * 16 + kl;
      v = W[o * INNER_SZ + (j + 1)] + W[o * INNER_SZ + (j + 1) * 65];
    }
    Wf2[idx] = (f16)v;
  }
  if (idx < 64) cvec[idx] = W[idx * INNER_SZ] + bias[idx];
}

__device__ constexpr int qb(int i) {   // kstep base of quad row i
  int b = i >> 4;
  return 16 * (b * (b + 1) / 2) + (i & 15) * (b + 1);
}

__device__ inline f16x8 mulsp(f16x2 sp, f16x8 wv) {
  f16x8 r;
#pragma unroll
  for (int e = 0; e < 4; ++e)
    ((f16x2*)&r)[e] = sp * ((const f16x2*)&wv)[e];
  return r;
}

// ---------------- main fused kernel ----------------
// grid 1024 x 128 threads (2 waves). Block tile: 64 rows x 64 cols.
// Wave w: all 64 rows x cols [32w, 32w+32); two 32x32x16 accs (row-halves).
// B-fragments loaded DIRECTLY global->VGPR (L2-resident Wf2, coalesced 16B/lane),
// register ring bb[8] = 8-kstep prefetch. No LDS / barriers / manual waitcnt in
// the K-loop; compiler emits counted vmcnt from register deps.
__global__ __launch_bounds__(128, 2) void cm_main(
    const float* __restrict__ x, const f16* __restrict__ Wf2,
    const float* __restrict__ cvec, const float* __restrict__ gamma,
    const float* __restrict__ beta, float* __restrict__ out) {
  __shared__ __align__(16) float yt[4096];   // epilogue transpose tile (16 KB)

  const int tid = threadIdx.x;
  const int lane = tid & 63;
  const int w = tid >> 6;            // ng: col-half owner
  const int c31 = lane & 31;
  const int h = lane >> 5;
  const long mbase = (long)blockIdx.x * 64;

  // ---- x: 2 full rows into registers (64 u32 = 64 f16x2) ----
  uint32_t xfu[2][32];
#pragma unroll
  for (int rr = 0; rr < 2; ++rr) {
    const float* xr = x + (size_t)(mbase + rr * 32 + c31) * 64;
#pragma unroll
    for (int g = 0; g < 8; ++g) {
      float4 a = *(const float4*)(xr + g * 8);
      float4 b = *(const float4*)(xr + g * 8 + 4);
      f16x2 p0 = {(f16)a.x, (f16)a.y}, p1 = {(f16)a.z, (f16)a.w};
      f16x2 p2 = {(f16)b.x, (f16)b.y}, p3 = {(f16)b.z, (f16)b.w};
      xfu[rr][g * 4 + 0] = __builtin_bit_cast(uint32_t, p0);
      xfu[rr][g * 4 + 1] = __builtin_bit_cast(uint32_t, p1);
      xfu[rr][g * 4 + 2] = __builtin_bit_cast(uint32_t, p2);
      xfu[rr][g * 4 + 3] = __builtin_bit_cast(uint32_t, p3);
    }
  }
  // A-windows: xw[rr][s] = x[row, s*16 + h*8 .. +8)
  f16x8 xw[2][4];
#pragma unroll
  for (int rr = 0; rr < 2; ++rr)
#pragma unroll
    for (int s = 0; s < 4; ++s) {
      u32x4 t;
#pragma unroll
      for (int k = 0; k < 4; ++k)
        t[k] = h ? xfu[rr][(2 * s + 1) * 4 + k] : xfu[rr][(2 * s) * 4 + k];
      xw[rr][s] = __builtin_bit_cast(f16x8, t);
    }

  // ---- B direct-load ring: lane granule = 2c+h (16B), wave half = w*1024 ----
  const char* bsrc = (const char*)Wf2 + w * 1024 + (2 * c31 + h) * 16;
  f16x8 bb[PD];
#pragma unroll
  for (int p = 0; p < PD; ++p)
    bb[p] = *(const f16x8*)(bsrc + (size_t)p * 2048);

  f32x16 acc0 = (f32x16)(0.0f);
  f32x16 acc1 = (f32x16)(0.0f);
  f16x2 sp0, sp1;

#define KSTEP(Q, S, LIN)                                                      \
  {                                                                           \
    f16x8 b_ = bb[(Q) & (PD - 1)];                                            \
    if ((Q) + PD < NQ)                                                        \
      bb[(Q) & (PD - 1)] = *(const f16x8*)(bsrc + (size_t)((Q) + PD) * 2048); \
    f16x8 a0_, a1_;                                                           \
    if (LIN) { a0_ = xw[0][(S)]; a1_ = xw[1][(S)]; }                          \
    else     { a0_ = mulsp(sp0, xw[0][(S)]); a1_ = mulsp(sp1, xw[1][(S)]); }  \
    acc0 = __builtin_amdgcn_mfma_f32_32x32x16_f16(a0_, b_, acc0, 0, 0, 0);    \
    acc1 = __builtin_amdgcn_mfma_f32_32x32x16_f16(a1_, b_, acc1, 0, 0, 0);    \
  }

  // ---- K-loop: 64 quad rows (1-4 ksteps each) + 4 linear; fully unrolled ----
#pragma unroll
  for (int I = 0; I < 64; ++I) {
    {  // splat x_i for both row-slots (compile-time register extract)
      uint32_t u0 = xfu[0][I >> 1], u1 = xfu[1][I >> 1];
      if (I & 1) { u0 >>= 16; u1 >>= 16; }
      u0 &= 0xffffu; u1 &= 0xffffu;
      sp0 = __builtin_bit_cast(f16x2, u0 | (u0 << 16));
      sp1 = __builtin_bit_cast(f16x2, u1 | (u1 << 16));
    }
#pragma unroll
    for (int S = 0; S <= (I >> 4); ++S) KSTEP(qb(I) + S, S, 0)
  }
  KSTEP(160, 0, 1) KSTEP(161, 1, 1) KSTEP(162, 2, 1) KSTEP(163, 3, 1)

  // ---- epilogue: transpose via swizzled LDS tile, LN over 64 cols, store ----
  {
    const int cg = w * 32 + c31;         // global col
    const int swz = (c31 & 7) << 4;
#pragma unroll
    for (int rq = 0; rq < 4; ++rq) {
      int b0 = cg * 256 + 0 * 128 + rq * 32 + h * 16;
      int b1 = cg * 256 + 1 * 128 + rq * 32 + h * 16;
      *(float4*)((char*)yt + (b0 ^ swz)) =
          make_float4(acc0[rq * 4 + 0], acc0[rq * 4 + 1], acc0[rq * 4 + 2], acc0[rq * 4 + 3]);
      *(float4*)((char*)yt + (b1 ^ swz)) =
          make_float4(acc1[rq * 4 + 0], acc1[rq * 4 + 1], acc1[rq * 4 + 2], acc1[rq * 4 + 3]);
    }
  }
  __syncthreads();
  {
    int row = tid >> 1, half = tid & 1;
    float y[32];
    float s = 0.f, qs = 0.f;
#pragma unroll
    for (int j = 0; j < 32; ++j) {
      int c = half * 32 + j;
      int byte = (c * 256 + row * 4) ^ ((c & 7) << 4);
      float v = *(const float*)((const char*)yt + byte);
      v += cvec[c];
      y[j] = v;
      s += v; qs += v * v;
    }
    s  += __shfl_xor(s, 1);
    qs += __shfl_xor(qs, 1);
    float mean = s * 0.015625f;
    float var = qs * 0.015625f - mean * mean;
    float rstd = rsqrtf(var + 1e-6f);
#pragma unroll
    for (int j = 0; j < 32; ++j) {
      int c = half * 32 + j;
      y[j] = gamma[c] * (y[j] - mean) * rstd + beta[c];
    }
    float* op = out + (size_t)(mbase + row) * 64 + half * 32;
#pragma unroll
    for (int j4 = 0; j4 < 8; ++j4)
      *(float4*)(op + j4 * 4) =
          make_float4(y[j4 * 4 + 0], y[j4 * 4 + 1], y[j4 * 4 + 2], y[j4 * 4 + 3]);
  }
#undef KSTEP
}

extern "C" void kernel_launch(void* const* d_in, const int* in_sizes, int n_in,
                              void* d_out, int out_size, void* d_ws, size_t ws_size,
                              hipStream_t stream) {
  const float* x     = (const float*)d_in[0];
  const float* W     = (const float*)d_in[1];
  const float* bias  = (const float*)d_in[2];
  const float* gamma = (const float*)d_in[3];
  const float* beta  = (const float*)d_in[4];
  float* out = (float*)d_out;

  f16* Wf2 = (f16*)d_ws;                                   // 164*1024*2 = 335872 B
  float* cvec = (float*)((char*)d_ws + NQ * 1024 * 2);     // 64 f32

  cm_prep<<<(NQ * 1024 + 255) / 256, 256, 0, stream>>>(W, bias, Wf2, cvec);
  cm_main<<<1024, 128, 0, stream>>>(x, Wf2, cvec, gamma, beta, out);
}

// Round 10
// 55.458 us; speedup vs baseline: 34.4441x; 34.4441x over previous
//
#include <hip/hip_runtime.h>
#include <stdint.h>
#include <stddef.h>

typedef _Float16 f16;
typedef _Float16 f16x2 __attribute__((ext_vector_type(2)));
typedef _Float16 f16x8 __attribute__((ext_vector_type(8)));
typedef float f32x16 __attribute__((ext_vector_type(16)));

#define INNER_SZ 4225
#define NQ 164          // ksteps: 160 quad (sym-folded, row-rounded) + 4 linear
#define PD 4            // register prefetch ring depth

// ---------------- prep: symmetric fold + granule-packed f16 ----------------
// Wf2 layout: [q][2048B] = [q][ng(2)][64 granules(16B)][8 f16], granule G = 2c+h.
// kstep q<160: quad row i, sub s: coeff[j = s*16 + h*8 + e] =
//   j<i: W[o][i,j]+W[o][j,i] ; j==i: W[o][i,i] ; j>i: 0
// kstep 160..163: linear terms W[o][0,j]+W[o][j,0].   (verified correct in R9)
__global__ __launch_bounds__(256) void cm_prep(const float* __restrict__ W,
                                               const float* __restrict__ bias,
                                               f16* __restrict__ Wf2,
                                               float* __restrict__ cvec) {
  int idx = blockIdx.x * 256 + threadIdx.x;
  if (idx < NQ * 1024) {
    int q   = idx >> 10;
    int r10 = idx & 1023;
    int ngh = r10 >> 9;
    int rr  = r10 & 511;
    int G   = rr >> 3;
    int e   = rr & 7;
    int c = G >> 1, hh = G & 1;
    int o = ngh * 32 + c;
    int kl = hh * 8 + e;
    float v = 0.f;
    if (q < 160) {
      int b, start;
      if (q < 16)      { b = 0; start = 0;  }
      else if (q < 48) { b = 1; start = 16; }
      else if (q < 96) { b = 2; start = 48; }
      else             { b = 3; start = 96; }
      int rel = q - start;
      int i = 16 * b + rel / (b + 1);
      int s = rel % (b + 1);
      int j = s * 16 + kl;
      if (j < i)
        v = W[o * INNER_SZ + (i + 1) * 65 + (j + 1)] +
            W[o * INNER_SZ + (j + 1) * 65 + (i + 1)];
      else if (j == i)
        v = W[o * INNER_SZ + (i + 1) * 65 + (i + 1)];
    } else {
      int j = (q - 160) * 16 + kl;
      v = W[o * INNER_SZ + (j + 1)] + W[o * INNER_SZ + (j + 1) * 65];
    }
    Wf2[idx] = (f16)v;
  }
  if (idx < 64) cvec[idx] = W[idx * INNER_SZ] + bias[idx];
}

__device__ constexpr int qb(int i) {   // kstep base of quad row i
  int b = i >> 4;
  return 16 * (b * (b + 1) / 2) + (i & 15) * (b + 1);
}

__device__ inline f16x8 mulsp(f16x2 sp, f16x8 wv) {
  f16x8 r;
#pragma unroll
  for (int e = 0; e < 4; ++e)
    ((f16x2*)&r)[e] = sp * ((const f16x2*)&wv)[e];
  return r;
}

// ---------------- main fused kernel ----------------
// grid 1024 x 128 threads (2 waves). Block tile: 64 rows x 64 cols.
// Wave w: all 64 rows x cols [32w, 32w+32); acc0 = rows 0-31, acc1 = rows 32-63.
// B-fragments: DIRECT global->VGPR (L2-resident Wf2), ring depth 4 (16 VGPRs).
// x: LDS tile; windows xw in regs (32 VGPRs); splat x_i via 1-i-ahead ds_read_u16.
// Live regs ~100 -> no spill (R9's failure). No barriers/waitcnt in K-loop.
__global__ __launch_bounds__(128, 2) void cm_main(
    const float* __restrict__ x, const f16* __restrict__ Wf2,
    const float* __restrict__ cvec, const float* __restrict__ gamma,
    const float* __restrict__ beta, float* __restrict__ out) {
  __shared__ union {
    f16 xs[64 * 72];     // 9216 B x tile (stride 72)
    float yt[4096];      // 16384 B epilogue transpose tile (aliases xs)
  } sm;

  const int tid = threadIdx.x;
  const int lane = tid & 63;
  const int w = tid >> 6;            // col-half owner
  const int c31 = lane & 31;
  const int h = lane >> 5;
  const long mbase = (long)blockIdx.x * 64;

  // ---- x tile -> LDS f16 [64][72] ----
#pragma unroll
  for (int it = 0; it < 4; ++it) {
    int idx = it * 1024 + tid * 8;
    int row = idx >> 6, col = idx & 63;
    const float* xp = x + (size_t)(mbase + row) * 64 + col;
    float4 a = *(const float4*)(xp);
    float4 b = *(const float4*)(xp + 4);
    f16x8 hv = {(f16)a.x, (f16)a.y, (f16)a.z, (f16)a.w,
                (f16)b.x, (f16)b.y, (f16)b.z, (f16)b.w};
    *(f16x8*)(sm.xs + row * 72 + col) = hv;
  }
  __syncthreads();

  const int r0 = c31, r1 = 32 + c31;
  // A-windows: xw[rr][s] = x[row, s*16 + h*8 .. +8)
  f16x8 xw[2][4];
#pragma unroll
  for (int s = 0; s < 4; ++s) {
    xw[0][s] = *(const f16x8*)(sm.xs + r0 * 72 + s * 16 + h * 8);
    xw[1][s] = *(const f16x8*)(sm.xs + r1 * 72 + s * 16 + h * 8);
  }

  // ---- B ring: lane granule = 2c+h (16B), wave half = w*1024 ----
  const char* bsrc = (const char*)Wf2 + w * 1024 + (2 * c31 + h) * 16;
  f16x8 bb[PD];
#pragma unroll
  for (int p = 0; p < PD; ++p)
    bb[p] = *(const f16x8*)(bsrc + (size_t)p * 2048);

  f32x16 acc0 = (f32x16)(0.0f);
  f32x16 acc1 = (f32x16)(0.0f);

  uint32_t un0 = *(const uint16_t*)(sm.xs + r0 * 72);   // x_i(0) prefetch
  uint32_t un1 = *(const uint16_t*)(sm.xs + r1 * 72);
  f16x2 sp0, sp1;

#define KSTEP(Q, S, LIN)                                                      \
  {                                                                           \
    f16x8 b_ = bb[(Q) & (PD - 1)];                                            \
    if ((Q) + PD < NQ)                                                        \
      bb[(Q) & (PD - 1)] = *(const f16x8*)(bsrc + (size_t)((Q) + PD) * 2048); \
    f16x8 a0_, a1_;                                                           \
    if (LIN) { a0_ = xw[0][(S)]; a1_ = xw[1][(S)]; }                          \
    else     { a0_ = mulsp(sp0, xw[0][(S)]); a1_ = mulsp(sp1, xw[1][(S)]); }  \
    acc0 = __builtin_amdgcn_mfma_f32_32x32x16_f16(a0_, b_, acc0, 0, 0, 0);    \
    acc1 = __builtin_amdgcn_mfma_f32_32x32x16_f16(a1_, b_, acc1, 0, 0, 0);    \
  }

  // ---- K-loop: 64 quad rows (1-4 ksteps each) + 4 linear; fully unrolled ----
#pragma unroll
  for (int I = 0; I < 64; ++I) {
    {
      uint32_t u0 = un0 & 0xffffu, u1 = un1 & 0xffffu;
      sp0 = __builtin_bit_cast(f16x2, u0 | (u0 << 16));
      sp1 = __builtin_bit_cast(f16x2, u1 | (u1 << 16));
    }
    if (I < 63) {   // prefetch x_i(I+1)
      un0 = *(const uint16_t*)(sm.xs + r0 * 72 + I + 1);
      un1 = *(const uint16_t*)(sm.xs + r1 * 72 + I + 1);
    }
#pragma unroll
    for (int S = 0; S <= (I >> 4); ++S) KSTEP(qb(I) + S, S, 0)
  }
  KSTEP(160, 0, 1) KSTEP(161, 1, 1) KSTEP(162, 2, 1) KSTEP(163, 3, 1)

  // ---- epilogue: transpose via swizzled LDS tile, LN over 64 cols, store ----
  __syncthreads();                       // xs reads done in both waves -> alias
  {
    const int cg = w * 32 + c31;         // global col
    const int swz = (c31 & 7) << 4;
#pragma unroll
    for (int rq = 0; rq < 4; ++rq) {
      int b0 = cg * 256 + 0 * 128 + rq * 32 + h * 16;
      int b1 = cg * 256 + 1 * 128 + rq * 32 + h * 16;
      *(float4*)((char*)sm.yt + (b0 ^ swz)) =
          make_float4(acc0[rq * 4 + 0], acc0[rq * 4 + 1], acc0[rq * 4 + 2], acc0[rq * 4 + 3]);
      *(float4*)((char*)sm.yt + (b1 ^ swz)) =
          make_float4(acc1[rq * 4 + 0], acc1[rq * 4 + 1], acc1[rq * 4 + 2], acc1[rq * 4 + 3]);
    }
  }
  __syncthreads();
  {
    int row = tid >> 1, half = tid & 1;
    float y[32];
    float s = 0.f, qs = 0.f;
#pragma unroll
    for (int j = 0; j < 32; ++j) {
      int c = half * 32 + j;
      int byte = (c * 256 + row * 4) ^ ((c & 7) << 4);
      float v = *(const float*)((const char*)sm.yt + byte);
      v += cvec[c];
      y[j] = v;
      s += v; qs += v * v;
    }
    s  += __shfl_xor(s, 1);
    qs += __shfl_xor(qs, 1);
    float mean = s * 0.015625f;
    float var = qs * 0.015625f - mean * mean;
    float rstd = rsqrtf(var + 1e-6f);
#pragma unroll
    for (int j = 0; j < 32; ++j) {
      int c = half * 32 + j;
      y[j] = gamma[c] * (y[j] - mean) * rstd + beta[c];
    }
    float* op = out + (size_t)(mbase + row) * 64 + half * 32;
#pragma unroll
    for (int j4 = 0; j4 < 8; ++j4)
      *(float4*)(op + j4 * 4) =
          make_float4(y[j4 * 4 + 0], y[j4 * 4 + 1], y[j4 * 4 + 2], y[j4 * 4 + 3]);
  }
#undef KSTEP
}

extern "C" void kernel_launch(void* const* d_in, const int* in_sizes, int n_in,
                              void* d_out, int out_size, void* d_ws, size_t ws_size,
                              hipStream_t stream) {
  const float* x     = (const float*)d_in[0];
  const float* W     = (const float*)d_in[1];
  const float* bias  = (const float*)d_in[2];
  const float* gamma = (const float*)d_in[3];
  const float* beta  = (const float*)d_in[4];
  float* out = (float*)d_out;

  f16* Wf2 = (f16*)d_ws;                                   // 164*1024*2 = 335872 B
  float* cvec = (float*)((char*)d_ws + NQ * 1024 * 2);     // 64 f32

  cm_prep<<<(NQ * 1024 + 255) / 256, 256, 0, stream>>>(W, bias, Wf2, cvec);
  cm_main<<<1024, 128, 0, stream>>>(x, Wf2, cvec, gamma, beta, out);
}

// Round 11
// 37.956 us; speedup vs baseline: 50.3263x; 1.4611x over previous
//
#include <hip/hip_runtime.h>
#include <stdint.h>
#include <stddef.h>

typedef _Float16 f16;
typedef _Float16 f16x2 __attribute__((ext_vector_type(2)));
typedef _Float16 f16x4 __attribute__((ext_vector_type(4)));
typedef _Float16 f16x8 __attribute__((ext_vector_type(8)));
typedef float f32x16 __attribute__((ext_vector_type(16)));

#define INNER_SZ 4225
#define NQ 164          // ksteps: 160 quad (sym-folded, row-rounded) + 4 linear
#define XSTR 72

// ---------------- prep: symmetric fold + granule-packed f16 (verified R9/R10) ----
// Wf2 layout: [q][2048B] = [q][ng(2)][64 granules(16B)][8 f16], granule G = 2c+h.
__global__ __launch_bounds__(256) void cm_prep(const float* __restrict__ W,
                                               const float* __restrict__ bias,
                                               f16* __restrict__ Wf2,
                                               float* __restrict__ cvec) {
  int idx = blockIdx.x * 256 + threadIdx.x;
  if (idx < NQ * 1024) {
    int q   = idx >> 10;
    int r10 = idx & 1023;
    int ngh = r10 >> 9;
    int rr  = r10 & 511;
    int G   = rr >> 3;
    int e   = rr & 7;
    int c = G >> 1, hh = G & 1;
    int o = ngh * 32 + c;
    int kl = hh * 8 + e;
    float v = 0.f;
    if (q < 160) {
      int b, start;
      if (q < 16)      { b = 0; start = 0;  }
      else if (q < 48) { b = 1; start = 16; }
      else if (q < 96) { b = 2; start = 48; }
      else             { b = 3; start = 96; }
      int rel = q - start;
      int i = 16 * b + rel / (b + 1);
      int s = rel % (b + 1);
      int j = s * 16 + kl;
      if (j < i)
        v = W[o * INNER_SZ + (i + 1) * 65 + (j + 1)] +
            W[o * INNER_SZ + (j + 1) * 65 + (i + 1)];
      else if (j == i)
        v = W[o * INNER_SZ + (i + 1) * 65 + (i + 1)];
    } else {
      int j = (q - 160) * 16 + kl;
      v = W[o * INNER_SZ + (j + 1)] + W[o * INNER_SZ + (j + 1) * 65];
    }
    Wf2[idx] = (f16)v;
  }
  if (idx < 64) cvec[idx] = W[idx * INNER_SZ] + bias[idx];
}

__device__ __forceinline__ f16x8 mulsp(f16x2 sp, f16x8 wv) {
  f16x8 r;
#pragma unroll
  for (int e = 0; e < 4; ++e)
    ((f16x2*)&r)[e] = sp * ((const f16x2*)&wv)[e];
  return r;
}

// K-segment body: 82 fully-unrolled ksteps, register W-ring depth 10.
// Static ring indices (qi%10 with unrolled qi) keep wr in VGPRs (rule #20).
template <int QLO>
__device__ __forceinline__ void kbody(f16x8 (&wr)[10], const char* bsrc,
                                      const f16* xs, int r0, int r1,
                                      const f16x8 (&xw0)[4], const f16x8 (&xw1)[4],
                                      f32x16& acc0, f32x16& acc1) {
  f16x2 sp0 = {}, sp1 = {};
#pragma unroll
  for (int qi = 0; qi < 82; ++qi) {
    const int q = QLO + qi;
    int i, s, lin;
    if (q >= 160) { i = 0; s = q - 160; lin = 1; }
    else {
      int b = (q < 16) ? 0 : (q < 48) ? 1 : (q < 96) ? 2 : 3;
      int st = (b == 0) ? 0 : (b == 1) ? 16 : (b == 2) ? 48 : 96;
      int rel = q - st;
      i = 16 * b + rel / (b + 1);
      s = rel % (b + 1);
      lin = 0;
    }
    bool newi = (qi == 0);
    if (qi > 0 && !lin) {
      int qp = q - 1;
      int bp = (qp < 16) ? 0 : (qp < 48) ? 1 : (qp < 96) ? 2 : 3;
      int stp = (bp == 0) ? 0 : (bp == 1) ? 16 : (bp == 2) ? 48 : 96;
      int ip = 16 * bp + (qp - stp) / (bp + 1);
      newi = (ip != i);
    }
    if (!lin && newi) {   // splat x_i for both 32-row groups
      uint32_t u0 = *(const uint16_t*)(xs + r0 * XSTR + i);
      uint32_t u1 = *(const uint16_t*)(xs + r1 * XSTR + i);
      sp0 = __builtin_bit_cast(f16x2, u0 | (u0 << 16));
      sp1 = __builtin_bit_cast(f16x2, u1 | (u1 << 16));
    }
    f16x8 b_ = wr[qi % 10];
    if (qi + 10 < 82)     // reload consumed slot for kstep qi+10 (dist ~700 cyc)
      wr[qi % 10] = *(const f16x8*)(bsrc + (size_t)(QLO + qi + 10) * 2048);
    f16x8 a0, a1;
    if (lin) { a0 = xw0[s]; a1 = xw1[s]; }
    else     { a0 = mulsp(sp0, xw0[s]); a1 = mulsp(sp1, xw1[s]); }
    acc0 = __builtin_amdgcn_mfma_f32_32x32x16_f16(a0, b_, acc0, 0, 0, 0);
    acc1 = __builtin_amdgcn_mfma_f32_32x32x16_f16(a1, b_, acc1, 0, 0, 0);
  }
}

// ---------------- main fused kernel ----------------
// grid 512 x 512 threads (8 waves). Block tile: 128 rows x 64 cols.
// Wave (rowg=w&1, ch=(w>>1)&1, seg=w>>2): rows rowg*64+[0,64) (acc0/acc1),
// cols ch*32+[0,32), ksteps [seg*82, seg*82+82). K-split-2 -> 4 waves/SIMD.
// B (W) operand: direct global->VGPR ring (L2-resident Wf2); no K-loop barriers.
__global__ __launch_bounds__(512, 4) void cm_main(
    const float* __restrict__ x, const f16* __restrict__ Wf2,
    const float* __restrict__ cvec, const float* __restrict__ gamma,
    const float* __restrict__ beta, float* __restrict__ out) {
  __shared__ __align__(16) union SM {
    f16 xs[128 * XSTR];                              // 18432 B (K-loop)
    struct { float red[128][64]; float yt[64 * 128]; } e;  // 32 KB + 32 KB (epilogue)
  } sm;

  const int tid = threadIdx.x;
  const int lane = tid & 63;
  const int w = tid >> 6;
  const int rowg = w & 1;
  const int ch = (w >> 1) & 1;
  const int seg = w >> 2;
  const int c31 = lane & 31;
  const int h = lane >> 5;
  const long mbase = (long)blockIdx.x * 128;

  // ---- W ring prologue: 10 slots, this wave's (ch, granule) stream ----
  const char* bsrc = (const char*)Wf2 + ch * 1024 + (2 * c31 + h) * 16;
  f16x8 wr[10];
  if (seg == 0) {
#pragma unroll
    for (int p = 0; p < 10; ++p)
      wr[p] = *(const f16x8*)(bsrc + (size_t)p * 2048);
  } else {
#pragma unroll
    for (int p = 0; p < 10; ++p)
      wr[p] = *(const f16x8*)(bsrc + (size_t)(82 + p) * 2048);
  }

  // ---- x tile -> LDS f16 [128][72] (overlaps W-load latency) ----
#pragma unroll
  for (int it = 0; it < 4; ++it) {
    int idx = it * 2048 + tid * 4;
    int row = idx >> 6, col = idx & 63;
    const float4 v = *(const float4*)(x + (size_t)(mbase + row) * 64 + col);
    f16x4 hv = {(f16)v.x, (f16)v.y, (f16)v.z, (f16)v.w};
    *(f16x4*)(sm.xs + row * XSTR + col) = hv;
  }
  __syncthreads();

  const int r0 = rowg * 64 + c31, r1 = rowg * 64 + 32 + c31;
  f16x8 xw0[4], xw1[4];
#pragma unroll
  for (int s = 0; s < 4; ++s) {
    xw0[s] = *(const f16x8*)(sm.xs + r0 * XSTR + s * 16 + h * 8);
    xw1[s] = *(const f16x8*)(sm.xs + r1 * XSTR + s * 16 + h * 8);
  }

  f32x16 acc0 = (f32x16)(0.0f);
  f32x16 acc1 = (f32x16)(0.0f);
  if (seg == 0) kbody<0>(wr, bsrc, sm.xs, r0, r1, xw0, xw1, acc0, acc1);
  else          kbody<82>(wr, bsrc, sm.xs, r0, r1, xw0, xw1, acc0, acc1);

  // ---- K-split reduction: seg1 -> LDS, seg0 adds ----
  __syncthreads();                    // xs dead; safe to alias
  if (seg == 1) {
#pragma unroll
    for (int r = 0; r < 16; ++r) {
      int rl = (r & 3) + 8 * (r >> 2) + 4 * h;
      sm.e.red[rowg * 64 + rl][ch * 32 + c31] = acc0[r];
      sm.e.red[rowg * 64 + 32 + rl][ch * 32 + c31] = acc1[r];
    }
  }
  __syncthreads();
  if (seg == 0) {
#pragma unroll
    for (int r = 0; r < 16; ++r) {
      int rl = (r & 3) + 8 * (r >> 2) + 4 * h;
      acc0[r] += sm.e.red[rowg * 64 + rl][ch * 32 + c31];
      acc1[r] += sm.e.red[rowg * 64 + 32 + rl][ch * 32 + c31];
    }
    // transpose write: yt[col][128 rows] f32, 512B/col, XOR-swizzled
    const int cg = ch * 32 + c31;
    const int swz = (c31 & 7) << 4;
#pragma unroll
    for (int rq = 0; rq < 4; ++rq) {
      int b0 = cg * 512 + rowg * 256 + 0 * 128 + rq * 32 + h * 16;
      int b1 = cg * 512 + rowg * 256 + 1 * 128 + rq * 32 + h * 16;
      *(float4*)((char*)sm.e.yt + (b0 ^ swz)) =
          make_float4(acc0[rq * 4 + 0], acc0[rq * 4 + 1], acc0[rq * 4 + 2], acc0[rq * 4 + 3]);
      *(float4*)((char*)sm.e.yt + (b1 ^ swz)) =
          make_float4(acc1[rq * 4 + 0], acc1[rq * 4 + 1], acc1[rq * 4 + 2], acc1[rq * 4 + 3]);
    }
  }
  __syncthreads();

  // ---- LayerNorm: 256 threads, one (row, col-half) each ----
  if (tid < 256) {
    int row = tid >> 1, half = tid & 1;
    float y[32];
    float s = 0.f, qs = 0.f;
#pragma unroll
    for (int j = 0; j < 32; ++j) {
      int c = half * 32 + j;
      int byte = (c * 512 + row * 4) ^ ((c & 7) << 4);
      float v = *(const float*)((const char*)sm.e.yt + byte);
      v += cvec[c];
      y[j] = v;
      s += v; qs += v * v;
    }
    s  += __shfl_xor(s, 1);
    qs += __shfl_xor(qs, 1);
    float mean = s * 0.015625f;
    float var = qs * 0.015625f - mean * mean;
    float rstd = rsqrtf(var + 1e-6f);
#pragma unroll
    for (int j = 0; j < 32; ++j) {
      int c = half * 32 + j;
      y[j] = gamma[c] * (y[j] - mean) * rstd + beta[c];
    }
    float* op = out + (size_t)(mbase + row) * 64 + half * 32;
#pragma unroll
    for (int j4 = 0; j4 < 8; ++j4)
      *(float4*)(op + j4 * 4) =
          make_float4(y[j4 * 4 + 0], y[j4 * 4 + 1], y[j4 * 4 + 2], y[j4 * 4 + 3]);
  }
}

extern "C" void kernel_launch(void* const* d_in, const int* in_sizes, int n_in,
                              void* d_out, int out_size, void* d_ws, size_t ws_size,
                              hipStream_t stream) {
  const float* x     = (const float*)d_in[0];
  const float* W     = (const float*)d_in[1];
  const float* bias  = (const float*)d_in[2];
  const float* gamma = (const float*)d_in[3];
  const float* beta  = (const float*)d_in[4];
  float* out = (float*)d_out;

  f16* Wf2 = (f16*)d_ws;                                   // 164*1024*2 = 335872 B
  float* cvec = (float*)((char*)d_ws + NQ * 1024 * 2);     // 64 f32

  cm_prep<<<(NQ * 1024 + 255) / 256, 256, 0, stream>>>(W, bias, Wf2, cvec);
  cm_main<<<512, 512, 0, stream>>>(x, Wf2, cvec, gamma, beta, out);
}

// Round 12
// 37.883 us; speedup vs baseline: 50.4234x; 1.0019x over previous
//
#include <hip/hip_runtime.h>
#include <stdint.h>
#include <stddef.h>

typedef _Float16 f16;
typedef _Float16 f16x2 __attribute__((ext_vector_type(2)));
typedef _Float16 f16x4 __attribute__((ext_vector_type(4)));
typedef _Float16 f16x8 __attribute__((ext_vector_type(8)));
typedef float f32x16 __attribute__((ext_vector_type(16)));
typedef uint32_t u32x4 __attribute__((ext_vector_type(4)));
typedef int i32x4 __attribute__((ext_vector_type(4)));

#define INNER_SZ 4225
#define NQ 164          // ksteps: 160 quad (sym-folded, row-rounded) + 4 linear
#define XSTR 72

// ---------------- prep: symmetric fold + granule-packed f16 (verified R9-R11) ----
// Wf2 layout: [q][2048B] = [q][ng(2)][64 granules(16B)][8 f16], granule G = 2c+h.
__global__ __launch_bounds__(256) void cm_prep(const float* __restrict__ W,
                                               const float* __restrict__ bias,
                                               f16* __restrict__ Wf2,
                                               float* __restrict__ cvec) {
  int idx = blockIdx.x * 256 + threadIdx.x;
  if (idx < NQ * 1024) {
    int q   = idx >> 10;
    int r10 = idx & 1023;
    int ngh = r10 >> 9;
    int rr  = r10 & 511;
    int G   = rr >> 3;
    int e   = rr & 7;
    int c = G >> 1, hh = G & 1;
    int o = ngh * 32 + c;
    int kl = hh * 8 + e;
    float v = 0.f;
    if (q < 160) {
      int b, start;
      if (q < 16)      { b = 0; start = 0;  }
      else if (q < 48) { b = 1; start = 16; }
      else if (q < 96) { b = 2; start = 48; }
      else             { b = 3; start = 96; }
      int rel = q - start;
      int i = 16 * b + rel / (b + 1);
      int s = rel % (b + 1);
      int j = s * 16 + kl;
      if (j < i)
        v = W[o * INNER_SZ + (i + 1) * 65 + (j + 1)] +
            W[o * INNER_SZ + (j + 1) * 65 + (i + 1)];
      else if (j == i)
        v = W[o * INNER_SZ + (i + 1) * 65 + (i + 1)];
    } else {
      int j = (q - 160) * 16 + kl;
      v = W[o * INNER_SZ + (j + 1)] + W[o * INNER_SZ + (j + 1) * 65];
    }
    Wf2[idx] = (f16)v;
  }
  if (idx < 64) cvec[idx] = W[idx * INNER_SZ] + bias[idx];
}

__device__ __forceinline__ f16x8 mulsp(f16x2 sp, f16x8 wv) {
  f16x8 r;
#pragma unroll
  for (int e = 0; e < 4; ++e)
    ((f16x2*)&r)[e] = sp * ((const f16x2*)&wv)[e];
  return r;
}

// K-segment body: 82 fully-unrolled ksteps.
// B-ring: 3 slots loaded by inline-asm global_load_dwordx4 (pinned regs, no remat),
// counted s_waitcnt vmcnt(2/1/0) + sched_barrier before each MFMA pair.
// Splat x_i: static register extract from xw + cross-half __shfl_xor(32) — no LDS.
template <int QLO>
__device__ __forceinline__ void kbody(const char* bsrc, int h,
                                      f16x8 (&xw0)[4], f16x8 (&xw1)[4],
                                      f32x16& acc0, f32x16& acc1) {
  i32x4 vb[3];
#pragma unroll
  for (int p = 0; p < 3; ++p)
    asm volatile("global_load_dwordx4 %0, %1, off"
                 : "=v"(vb[p])
                 : "v"(bsrc + (size_t)(QLO + p) * 2048));
  f16x2 sp0 = {}, sp1 = {};
#pragma unroll
  for (int qi = 0; qi < 82; ++qi) {
    const int q = QLO + qi;
    int i, s, lin;
    if (q >= 160) { i = 0; s = q - 160; lin = 1; }
    else {
      int b = (q < 16) ? 0 : (q < 48) ? 1 : (q < 96) ? 2 : 3;
      int st = (b == 0) ? 0 : (b == 1) ? 16 : (b == 2) ? 48 : 96;
      int rel = q - st;
      i = 16 * b + rel / (b + 1);
      s = rel % (b + 1);
      lin = 0;
    }
    bool newi = (qi == 0);
    if (qi > 0 && !lin) {
      int qp = q - 1;
      int bp = (qp < 16) ? 0 : (qp < 48) ? 1 : (qp < 96) ? 2 : 3;
      int stp = (bp == 0) ? 0 : (bp == 1) ? 16 : (bp == 2) ? 48 : 96;
      int ip = 16 * bp + (qp - stp) / (bp + 1);
      newi = (ip != i);
    }
    if (!lin && newi) {
      // x_i = element (i&7) of half-(i>>3)&1 window (i>>4); broadcast across halves.
      const int si = i >> 4, hb = (i >> 3) & 1, wd = (i & 7) >> 1, pp = i & 1;
      uint32_t ow0 = __builtin_bit_cast(u32x4, xw0[si])[wd];
      uint32_t ow1 = __builtin_bit_cast(u32x4, xw1[si])[wd];
      uint32_t pw0 = (uint32_t)__shfl_xor((int)ow0, 32, 64);
      uint32_t pw1 = (uint32_t)__shfl_xor((int)ow1, 32, 64);
      uint32_t sel0 = (h == hb) ? ow0 : pw0;
      uint32_t sel1 = (h == hb) ? ow1 : pw1;
      uint32_t v0 = pp ? (sel0 >> 16) : (sel0 & 0xffffu);
      uint32_t v1 = pp ? (sel1 >> 16) : (sel1 & 0xffffu);
      sp0 = __builtin_bit_cast(f16x2, v0 | (v0 << 16));
      sp1 = __builtin_bit_cast(f16x2, v1 | (v1 << 16));
    }
    f16x8 a0, a1;
    if (lin) { a0 = xw0[s]; a1 = xw1[s]; }
    else     { a0 = mulsp(sp0, xw0[s]); a1 = mulsp(sp1, xw1[s]); }
    // counted wait: outstanding allowed = min(2, 81 - qi)
    {
      const int out = (81 - qi < 2) ? (81 - qi) : 2;
      if (out == 2)      asm volatile("s_waitcnt vmcnt(2)" ::: "memory");
      else if (out == 1) asm volatile("s_waitcnt vmcnt(1)" ::: "memory");
      else               asm volatile("s_waitcnt vmcnt(0)" ::: "memory");
      __builtin_amdgcn_sched_barrier(0);
    }
    f16x8 b_ = __builtin_bit_cast(f16x8, vb[qi % 3]);
    acc0 = __builtin_amdgcn_mfma_f32_32x32x16_f16(a0, b_, acc0, 0, 0, 0);
    acc1 = __builtin_amdgcn_mfma_f32_32x32x16_f16(a1, b_, acc1, 0, 0, 0);
    if (qi + 3 < 82)
      asm volatile("global_load_dwordx4 %0, %1, off"
                   : "=v"(vb[qi % 3])
                   : "v"(bsrc + (size_t)(q + 3) * 2048));
  }
}

// ---------------- main fused kernel ----------------
// grid 512 x 512 threads (8 waves). Block tile: 128 rows x 64 cols.
// Wave (rowg=w&1, ch=(w>>1)&1, seg=w>>2): rows rowg*64+[0,64) (acc0/acc1),
// cols ch*32+[0,32), ksteps [seg*82, (seg+1)*82). 2 blocks/CU -> 4 waves/SIMD.
__global__ __launch_bounds__(512, 4) void cm_main(
    const float* __restrict__ x, const f16* __restrict__ Wf2,
    const float* __restrict__ cvec, const float* __restrict__ gamma,
    const float* __restrict__ beta, float* __restrict__ out) {
  __shared__ __align__(16) union SM {
    f16 xs[128 * XSTR];                              // 18432 B (prologue)
    struct { float red[128][64]; float yt[64 * 128]; } e;  // 64 KB (epilogue)
  } sm;

  const int tid = threadIdx.x;
  const int lane = tid & 63;
  const int w = tid >> 6;
  const int rowg = w & 1;
  const int ch = (w >> 1) & 1;
  const int seg = w >> 2;
  const int c31 = lane & 31;
  const int h = lane >> 5;
  const long mbase = (long)blockIdx.x * 128;

  const char* bsrc = (const char*)Wf2 + ch * 1024 + (2 * c31 + h) * 16;

  // ---- x tile -> LDS f16 [128][72] ----
#pragma unroll
  for (int it = 0; it < 4; ++it) {
    int idx = it * 2048 + tid * 4;
    int row = idx >> 6, col = idx & 63;
    const float4 v = *(const float4*)(x + (size_t)(mbase + row) * 64 + col);
    f16x4 hv = {(f16)v.x, (f16)v.y, (f16)v.z, (f16)v.w};
    *(f16x4*)(sm.xs + row * XSTR + col) = hv;
  }
  __syncthreads();   // xs visible; also drains all vmcnt (clean count for kbody)

  const int r0 = rowg * 64 + c31, r1 = rowg * 64 + 32 + c31;
  f16x8 xw0[4], xw1[4];
#pragma unroll
  for (int s = 0; s < 4; ++s) {
    xw0[s] = *(const f16x8*)(sm.xs + r0 * XSTR + s * 16 + h * 8);
    xw1[s] = *(const f16x8*)(sm.xs + r1 * XSTR + s * 16 + h * 8);
  }
#pragma unroll
  for (int s = 0; s < 4; ++s)            // pin xw in registers (block remat-from-LDS)
    asm volatile("" : "+v"(xw0[s]), "+v"(xw1[s]));

  f32x16 acc0 = (f32x16)(0.0f);
  f32x16 acc1 = (f32x16)(0.0f);
  if (seg == 0) kbody<0>(bsrc, h, xw0, xw1, acc0, acc1);
  else          kbody<82>(bsrc, h, xw0, xw1, acc0, acc1);

  // ---- K-split reduction: seg1 -> LDS, seg0 adds (verified R11) ----
  __syncthreads();                    // xs dead; safe to alias
  if (seg == 1) {
#pragma unroll
    for (int r = 0; r < 16; ++r) {
      int rl = (r & 3) + 8 * (r >> 2) + 4 * h;
      sm.e.red[rowg * 64 + rl][ch * 32 + c31] = acc0[r];
      sm.e.red[rowg * 64 + 32 + rl][ch * 32 + c31] = acc1[r];
    }
  }
  __syncthreads();
  if (seg == 0) {
#pragma unroll
    for (int r = 0; r < 16; ++r) {
      int rl = (r & 3) + 8 * (r >> 2) + 4 * h;
      acc0[r] += sm.e.red[rowg * 64 + rl][ch * 32 + c31];
      acc1[r] += sm.e.red[rowg * 64 + 32 + rl][ch * 32 + c31];
    }
    const int cg = ch * 32 + c31;
    const int swz = (c31 & 7) << 4;
#pragma unroll
    for (int rq = 0; rq < 4; ++rq) {
      int b0 = cg * 512 + rowg * 256 + 0 * 128 + rq * 32 + h * 16;
      int b1 = cg * 512 + rowg * 256 + 1 * 128 + rq * 32 + h * 16;
      *(float4*)((char*)sm.e.yt + (b0 ^ swz)) =
          make_float4(acc0[rq * 4 + 0], acc0[rq * 4 + 1], acc0[rq * 4 + 2], acc0[rq * 4 + 3]);
      *(float4*)((char*)sm.e.yt + (b1 ^ swz)) =
          make_float4(acc1[rq * 4 + 0], acc1[rq * 4 + 1], acc1[rq * 4 + 2], acc1[rq * 4 + 3]);
    }
  }
  __syncthreads();

  // ---- LayerNorm: 256 threads, one (row, col-half) each ----
  if (tid < 256) {
    int row = tid >> 1, half = tid & 1;
    float y[32];
    float s = 0.f, qs = 0.f;
#pragma unroll
    for (int j = 0; j < 32; ++j) {
      int c = half * 32 + j;
      int byte = (c * 512 + row * 4) ^ ((c & 7) << 4);
      float v = *(const float*)((const char*)sm.e.yt + byte);
      v += cvec[c];
      y[j] = v;
      s += v; qs += v * v;
    }
    s  += __shfl_xor(s, 1);
    qs += __shfl_xor(qs, 1);
    float mean = s * 0.015625f;
    float var = qs * 0.015625f - mean * mean;
    float rstd = rsqrtf(var + 1e-6f);
#pragma unroll
    for (int j = 0; j < 32; ++j) {
      int c = half * 32 + j;
      y[j] = gamma[c] * (y[j] - mean) * rstd + beta[c];
    }
    float* op = out + (size_t)(mbase + row) * 64 + half * 32;
#pragma unroll
    for (int j4 = 0; j4 < 8; ++j4)
      *(float4*)(op + j4 * 4) =
          make_float4(y[j4 * 4 + 0], y[j4 * 4 + 1], y[j4 * 4 + 2], y[j4 * 4 + 3]);
  }
}

extern "C" void kernel_launch(void* const* d_in, const int* in_sizes, int n_in,
                              void* d_out, int out_size, void* d_ws, size_t ws_size,
                              hipStream_t stream) {
  const float* x     = (const float*)d_in[0];
  const float* W     = (const float*)d_in[1];
  const float* bias  = (const float*)d_in[2];
  const float* gamma = (const float*)d_in[3];
  const float* beta  = (const float*)d_in[4];
  float* out = (float*)d_out;

  f16* Wf2 = (f16*)d_ws;                                   // 164*1024*2 = 335872 B
  float* cvec = (float*)((char*)d_ws + NQ * 1024 * 2);     // 64 f32

  cm_prep<<<(NQ * 1024 + 255) / 256, 256, 0, stream>>>(W, bias, Wf2, cvec);
  cm_main<<<512, 512, 0, stream>>>(x, Wf2, cvec, gamma, beta, out);
}